// Round 11
// baseline (260.577 us; speedup 1.0000x reference)
//
#include <hip/hip_runtime.h>

#define D_DIM 256
#define K_CODES 1024
#define MARGIN 4e-4f
#define RCAP 32

typedef __attribute__((ext_vector_type(8))) short short8;
typedef __attribute__((ext_vector_type(4))) float f32x4;

// RNE f32 -> bf16 bits (finite inputs; validated rounds 6-10)
__device__ __forceinline__ unsigned int bfr(float x) {
    unsigned int u = __float_as_uint(x);
    return (u + 0x7FFFu + ((u >> 16) & 1u)) >> 16;
}
__device__ __forceinline__ float bf2f(unsigned int b) {
    return __uint_as_float(b << 16);
}
__device__ __forceinline__ void gload16(const void* g, void* l) {
    __builtin_amdgcn_global_load_lds(
        (const __attribute__((address_space(1))) void*)g,
        (__attribute__((address_space(3))) void*)l, 16, 0, 0);
}

// ---------------------------------------------------------------------------
// k_prep: [0,128) z2 | [128,132) e2 | [132,2180) z split+transpose+swz |
//         [2180,2196) e split+swz | [2196,2228) rowCnt zero (+lossAcc)
// (unchanged from validated rounds 9/10)
// ---------------------------------------------------------------------------
__global__ __launch_bounds__(256) void k_prep(const float* __restrict__ z,
                                              const float* __restrict__ e,
                                              float* __restrict__ z2,
                                              float* __restrict__ e2,
                                              unsigned short* __restrict__ zhi,
                                              unsigned short* __restrict__ zlo,
                                              unsigned short* __restrict__ ehi,
                                              unsigned short* __restrict__ elo,
                                              int* __restrict__ rowCnt,
                                              float* __restrict__ lossAcc) {
    __shared__ float tile[64][65];
    const int bi = blockIdx.x;
    const int t  = threadIdx.x;
    if (bi < 128) {                    // ---- z2 ----
        int n = bi * 256 + t;
        int b = n >> 10, nl = n & 1023;
        const float* p = z + (size_t)b * (D_DIM * 1024) + nl;
        float s = 0.f;
#pragma unroll 8
        for (int d = 0; d < D_DIM; ++d) {
            float v = p[(size_t)d * 1024];
            s = fmaf(v, v, s);
        }
        z2[n] = s;
    } else if (bi < 132) {             // ---- e2 ----
        int k = (bi - 128) * 256 + t;
        const float4* p = (const float4*)(e + (size_t)k * D_DIM);
        float s = 0.f;
#pragma unroll 4
        for (int c = 0; c < D_DIM / 4; ++c) {
            float4 v = p[c];
            s = fmaf(v.x, v.x, s); s = fmaf(v.y, v.y, s);
            s = fmaf(v.z, v.z, s); s = fmaf(v.w, v.w, s);
        }
        e2[k] = s;
    } else if (bi < 2180) {            // ---- z split + transpose + swizzle ----
        int bb = bi - 132;
        int n0 = (bb & 511) * 64;
        int d0 = (bb >> 9) * 64;
        int b = n0 >> 10, nl0 = n0 & 1023;
#pragma unroll 4
        for (int i = 0; i < 16; ++i) {
            int flat = i * 256 + t;
            int dd = flat >> 6, j = flat & 63;
            tile[dd][j] = z[(size_t)b * (D_DIM * 1024) +
                            (size_t)(d0 + dd) * 1024 + nl0 + j];
        }
        __syncthreads();
#pragma unroll
        for (int i = 0; i < 4; ++i) {
            int flat = i * 256 + t;
            int row = flat >> 4, ch = flat & 15;
            int s8p = ch >> 1, half = ch & 1;
            int s8  = s8p ^ (row & 7);
            int ddl = s8 * 8 + half * 4;
            unsigned int h[4], l[4];
#pragma unroll
            for (int m2 = 0; m2 < 4; ++m2) {
                float v = tile[ddl + m2][row];
                h[m2] = bfr(v);
                l[m2] = bfr(v - bf2f(h[m2]));
            }
            uint2 ph = { h[0] | (h[1] << 16), h[2] | (h[3] << 16) };
            uint2 pl = { l[0] | (l[1] << 16), l[2] | (l[3] << 16) };
            size_t off = (size_t)(n0 + row) * 256 + d0 + s8p * 8 + half * 4;
            *(uint2*)(zhi + off) = ph;
            *(uint2*)(zlo + off) = pl;
        }
    } else if (bi < 2196) {            // ---- e split + swizzle ----
        int k0 = (bi - 2180) * 64;
#pragma unroll 4
        for (int i = 0; i < 16; ++i) {
            int flat = i * 256 + t;
            int row = flat >> 6, ch = flat & 63;
            int slab = ch >> 4, s8p = (ch >> 1) & 7, half = ch & 1;
            int s8 = s8p ^ (row & 7);
            int d  = slab * 64 + s8 * 8 + half * 4;
            float4 v = *(const float4*)(e + (size_t)(k0 + row) * 256 + d);
            unsigned int h0 = bfr(v.x), h1 = bfr(v.y), h2 = bfr(v.z), h3 = bfr(v.w);
            unsigned int l0 = bfr(v.x - bf2f(h0)), l1 = bfr(v.y - bf2f(h1));
            unsigned int l2 = bfr(v.z - bf2f(h2)), l3 = bfr(v.w - bf2f(h3));
            uint2 ph = { h0 | (h1 << 16), h2 | (h3 << 16) };
            uint2 pl = { l0 | (l1 << 16), l2 | (l3 << 16) };
            size_t off = (size_t)(k0 + row) * 256 + slab * 64 + s8p * 8 + half * 4;
            *(uint2*)(ehi + off) = ph;
            *(uint2*)(elo + off) = pl;
        }
    } else {                           // ---- rowCnt zero ----
        int bb = bi - 2196;
        if (bb == 0 && t == 0) lossAcc[0] = 0.f;
#pragma unroll
        for (int i = 0; i < 4; ++i)
            rowCnt[bb * 1024 + i * 256 + t] = 0;
    }
}

// ---------------------------------------------------------------------------
// k_score (validated round 10) — ONE CHANGE: XCD sibling co-location.
// Round 10 decode (rb = bid>>3, kc = bid&7) round-robins a row-block's 8
// kc-siblings across the 8 XCD L2s -> the 32 MB zhi/zlo was HBM-fetched ~4x
// (FETCH 132 MB, k_score HBM-latency-bound at ~1.2 TB/s). New decode
// kc = bid>>8, rb = bid&255: all 8 siblings have index == rb (mod 8) -> same
// XCD under the empirical xcd = idx%8 round-robin; per XCD the 32 pinned
// rb A-tiles (2 MB) + B (1 MB) fit its 4 MB L2 and persist across all 4
// resident generations -> A read from HBM exactly once. Pure relabeling.
// ---------------------------------------------------------------------------
__global__ __launch_bounds__(256) void k_score(
        const unsigned short* __restrict__ zhi,
        const unsigned short* __restrict__ zlo,
        const unsigned short* __restrict__ ehi,
        const unsigned short* __restrict__ elo,
        const float* __restrict__ e2,
        int* __restrict__ rowCnt, uint2* __restrict__ rowCand) {
    __shared__ unsigned short Ah[8192], Al[8192], Bh[8192], Bl[8192]; // 64 KB

    const int t    = threadIdx.x;
    const int lane = t & 63;
    const int w    = t >> 6;
    const int wrow = w >> 1, wcol = w & 1;
    const int kc   = blockIdx.x >> 8;      // XCD co-location decode
    const int rb   = blockIdx.x & 255;
    const int n0   = rb * 128, k0 = kc * 128;
    const int c    = lane & 15, kq = lane >> 4;

    f32x4 acc[4][4];
#pragma unroll
    for (int rf = 0; rf < 4; ++rf)
#pragma unroll
        for (int cf = 0; cf < 4; ++cf)
            acc[rf][cf] = (f32x4){0.f, 0.f, 0.f, 0.f};

    for (int sl = 0; sl < 4; ++sl) {
#pragma unroll
        for (int i = 0; i < 4; ++i) {
            int slot = i * 256 + t;
            int row = slot >> 3, s16 = slot & 7;
            size_t aoff = (size_t)(n0 + row) * 256 + sl * 64 + s16 * 8;
            size_t boff = (size_t)(k0 + row) * 256 + sl * 64 + s16 * 8;
            int dbase = (i * 256 + w * 64) * 8;
            gload16(zhi + aoff, &Ah[dbase]);
            gload16(zlo + aoff, &Al[dbase]);
            gload16(ehi + boff, &Bh[dbase]);
            gload16(elo + boff, &Bl[dbase]);
        }
        __syncthreads();
#pragma unroll
        for (int ks = 0; ks < 2; ++ks) {
            short8 ah[4], al[4], bh[4], bl[4];
#pragma unroll
            for (int rf = 0; rf < 4; ++rf) {
                int rl = wrow * 64 + rf * 16 + c;
                int sp = (ks * 4 + kq) ^ (rl & 7);
                ah[rf] = *(const short8*)&Ah[rl * 64 + sp * 8];
                al[rf] = *(const short8*)&Al[rl * 64 + sp * 8];
            }
#pragma unroll
            for (int cf = 0; cf < 4; ++cf) {
                int cl = wcol * 64 + cf * 16 + c;
                int sp = (ks * 4 + kq) ^ (cl & 7);
                bh[cf] = *(const short8*)&Bh[cl * 64 + sp * 8];
                bl[cf] = *(const short8*)&Bl[cl * 64 + sp * 8];
            }
#pragma unroll
            for (int rf = 0; rf < 4; ++rf)
#pragma unroll
                for (int cf = 0; cf < 4; ++cf) {
                    acc[rf][cf] = __builtin_amdgcn_mfma_f32_16x16x32_bf16(ah[rf], bh[cf], acc[rf][cf], 0, 0, 0);
                    acc[rf][cf] = __builtin_amdgcn_mfma_f32_16x16x32_bf16(al[rf], bh[cf], acc[rf][cf], 0, 0, 0);
                    acc[rf][cf] = __builtin_amdgcn_mfma_f32_16x16x32_bf16(ah[rf], bl[cf], acc[rf][cf], 0, 0, 0);
                }
        }
        __syncthreads();
    }

    // ---- epilogue: s = e2[k] - 2*ze; capture s <= chunkmin + MARGIN ----
    float e2r[4];
#pragma unroll
    for (int cf = 0; cf < 4; ++cf) e2r[cf] = e2[k0 + wcol * 64 + cf * 16 + c];

    float rmin[4][4];
#pragma unroll
    for (int rf = 0; rf < 4; ++rf)
#pragma unroll
        for (int reg = 0; reg < 4; ++reg) {
            float mm = 3.4e38f;
#pragma unroll
            for (int cf = 0; cf < 4; ++cf)
                mm = fminf(mm, fmaf(-2.f, acc[rf][cf][reg], e2r[cf]));
            rmin[rf][reg] = mm;
        }
#pragma unroll
    for (int m = 1; m < 16; m <<= 1)
#pragma unroll
        for (int rf = 0; rf < 4; ++rf)
#pragma unroll
            for (int reg = 0; reg < 4; ++reg)
                rmin[rf][reg] = fminf(rmin[rf][reg],
                                      __shfl_xor(rmin[rf][reg], m, 64));

#pragma unroll
    for (int rf = 0; rf < 4; ++rf)
#pragma unroll
        for (int cf = 0; cf < 4; ++cf)
#pragma unroll
            for (int reg = 0; reg < 4; ++reg) {
                float s = fmaf(-2.f, acc[rf][cf][reg], e2r[cf]);
                if (s <= rmin[rf][reg] + MARGIN) {
                    int n = n0 + wrow * 64 + rf * 16 + kq * 4 + reg;
                    int k = k0 + wcol * 64 + cf * 16 + c;
                    int pos = atomicAdd(&rowCnt[n], 1);
                    if (pos < RCAP) {
                        uint2 cd; cd.x = (unsigned)k; cd.y = __float_as_uint(s);
                        rowCand[n * RCAP + pos] = cd;
                    }
                }
            }
}

// ---------------------------------------------------------------------------
// k_select: global-min filter + exact rescore of survivors (validated r10).
// ---------------------------------------------------------------------------
__global__ __launch_bounds__(256) void k_select(
        const float* __restrict__ z, const float* __restrict__ e,
        const float* __restrict__ z2a, const float* __restrict__ e2,
        const int* __restrict__ rowCnt, const uint2* __restrict__ rowCand,
        float* __restrict__ outIdx, int* __restrict__ wsIdx) {
    const int t = threadIdx.x, lane = t & 63, w = t >> 6;
    const int wid = blockIdx.x * 4 + w;       // 0..4095
    for (int rr = 0; rr < 8; ++rr) {
        const int n = wid * 8 + rr;
        const int cnt = rowCnt[n];
        const float* zrow = z + (size_t)(n >> 10) * (D_DIM * 1024) + (n & 1023);
        unsigned long long key = 0xFFFFFFFFFFFFFFFFULL;
        if (cnt <= RCAP) {
            float s = 3.4e38f;
            int   k = 0;
            if (lane < cnt) {
                uint2 cd = rowCand[n * RCAP + lane];
                k = (int)cd.x;
                s = __uint_as_float(cd.y);
            }
            float gmin = s;
#pragma unroll
            for (int m = 1; m < 64; m <<= 1)
                gmin = fminf(gmin, __shfl_xor(gmin, m, 64));
            bool surv = (lane < cnt) && (s <= gmin + MARGIN);
            unsigned long long bal = __ballot(surv);
            if (__popcll(bal) == 1) {            // sole survivor == argmin
                if (surv) { outIdx[n] = (float)k; wsIdx[n] = k; }
                continue;                         // bal wave-uniform
            }
            if (surv) {
                const float* er = e + (size_t)k * D_DIM;
                float ze = 0.f;
#pragma unroll 8
                for (int d = 0; d < D_DIM; ++d)
                    ze = fmaf(zrow[(size_t)d * 1024], er[d], ze);
                float t1 = z2a[n] + e2[k];
                float dist = fmaf(-2.f, ze, t1);
                key = ((unsigned long long)__float_as_uint(dist) << 32) |
                      (unsigned int)k;
            }
        } else {                      // deterministic fallback: full scan
            const float z2r = z2a[n];
            for (int j = 0; j < 16; ++j) {
                int k = lane * 16 + j;
                const float* er = e + (size_t)k * D_DIM;
                float ze = 0.f;
#pragma unroll 8
                for (int d = 0; d < D_DIM; ++d)
                    ze = fmaf(zrow[(size_t)d * 1024], er[d], ze);
                float t1 = z2r + e2[k];
                float dist = fmaf(-2.f, ze, t1);
                unsigned long long kk =
                    ((unsigned long long)__float_as_uint(dist) << 32) |
                    (unsigned int)k;
                if (kk < key) key = kk;
            }
        }
#pragma unroll
        for (int m = 1; m < 64; m <<= 1) {
            unsigned long long o = __shfl_xor(key, m, 64);
            if (o < key) key = o;
        }
        if (lane == 0) {
            int k = (int)(unsigned int)(key & 0xFFFFFFFFULL);
            outIdx[n] = (float)k;
            wsIdx[n]  = k;
        }
    }
}

// ---------------------------------------------------------------------------
// Epilogue (re-tiled): 32 rows x 256 d per block, grid 1024. Round 10 used
// 64-row blocks (64 KB LDS, grid 512 = 2 blocks/CU — grid- AND LDS-limited).
// Now 32 KB LDS, 4 blocks/CU. Same validated gather/ST/loss logic.
// ---------------------------------------------------------------------------
__global__ __launch_bounds__(256) void k_epilogue(const float* __restrict__ z,
                                                  const float* __restrict__ e,
                                                  const int* __restrict__ wsIdx,
                                                  float* __restrict__ outZ,
                                                  float* __restrict__ lossAcc) {
    __shared__ float4 zq4[32][64];
    __shared__ int idxs[32];
    const int t = threadIdx.x;
    const int n0 = blockIdx.x * 32;
    const int b = n0 >> 10, nl0 = n0 & 1023;

    if (t < 32) idxs[t] = wsIdx[n0 + t];
    __syncthreads();

#pragma unroll
    for (int j = 0; j < 8; ++j) {
        int flat = j * 256 + t;
        int i  = flat >> 6;          // row 0..31
        int c4 = flat & 63;
        float4 v = *(const float4*)(e + (size_t)idxs[i] * D_DIM + c4 * 4);
        zq4[i][c4 ^ (i & 7)] = v;
    }
    __syncthreads();

    const int i  = t & 31;           // row
    const int dg = t >> 5;           // d-group 0..7 (8 c4 each)
    const float* zp = z    + (size_t)b * (D_DIM * 1024) + nl0 + i;
    float*       op = outZ + (size_t)b * (D_DIM * 1024) + nl0 + i;
    float s = 0.f;
#pragma unroll 4
    for (int c = 0; c < 8; ++c) {
        int c4 = dg * 8 + c;
        float4 qv = zq4[i][c4 ^ (i & 7)];
        int d = c4 * 4;
        float zv, df;
        zv = zp[(size_t)(d + 0) * 1024]; df = qv.x - zv; s = fmaf(df, df, s); op[(size_t)(d + 0) * 1024] = zv + df;
        zv = zp[(size_t)(d + 1) * 1024]; df = qv.y - zv; s = fmaf(df, df, s); op[(size_t)(d + 1) * 1024] = zv + df;
        zv = zp[(size_t)(d + 2) * 1024]; df = qv.z - zv; s = fmaf(df, df, s); op[(size_t)(d + 2) * 1024] = zv + df;
        zv = zp[(size_t)(d + 3) * 1024]; df = qv.w - zv; s = fmaf(df, df, s); op[(size_t)(d + 3) * 1024] = zv + df;
    }
#pragma unroll
    for (int off = 32; off > 0; off >>= 1) s += __shfl_down(s, off, 64);
    if ((t & 63) == 0) atomicAdd(lossAcc, s);
}

__global__ void k_final(const float* __restrict__ lossAcc,
                        float* __restrict__ outLoss) {
    float m = lossAcc[0] * (1.0f / 8388608.0f);
    outLoss[0] = m + 0.25f * m;
}

// ---------------------------------------------------------------------------
extern "C" void kernel_launch(void* const* d_in, const int* in_sizes, int n_in,
                              void* d_out, int out_size, void* d_ws, size_t ws_size,
                              hipStream_t stream) {
    const float* z = (const float*)d_in[0];   // (32,256,32,32)
    const float* e = (const float*)d_in[1];   // (1024,256)
    float* out     = (float*)d_out;
    float* outIdx  = out + 8388608;
    float* outLoss = out + 8421376;

    float* z2      = (float*)d_ws;                        // 32768 f
    float* e2      = z2 + 32768;                          // 1024 f
    float* lossAcc = e2 + 1024;                           // 1 f
    int*   rowCnt  = (int*)(lossAcc + 1);                 // 32768 i
    uintptr_t p = (uintptr_t)(rowCnt + 32768);
    p = (p + 255) & ~(uintptr_t)255;
    uint2* rowCand = (uint2*)p;                           // 32768*32 uint2 = 8 MB
    unsigned short* zhi = (unsigned short*)(rowCand + 32768 * RCAP); // 16 MB
    unsigned short* zlo = zhi + 8388608;                  // 16 MB
    unsigned short* ehi = zlo + 8388608;                  // 512 KB
    unsigned short* elo = ehi + 262144;                   // 512 KB
    int*   wsIdx   = (int*)(elo + 262144);                // 32768 i

    k_prep<<<2228, 256, 0, stream>>>(z, e, z2, e2, zhi, zlo, ehi, elo,
                                     rowCnt, lossAcc);
    k_score<<<2048, 256, 0, stream>>>(zhi, zlo, ehi, elo, e2, rowCnt, rowCand);
    k_select<<<1024, 256, 0, stream>>>(z, e, z2, e2, rowCnt, rowCand,
                                       outIdx, wsIdx);
    k_epilogue<<<1024, 256, 0, stream>>>(z, e, wsIdx, out, lossAcc);
    k_final<<<1, 1, 0, stream>>>(lossAcc, outLoss);
}

// Round 12
// 242.667 us; speedup vs baseline: 1.0738x; 1.0738x over previous
//
#include <hip/hip_runtime.h>
#include <hip/hip_fp16.h>

#define D_DIM 256
#define K_CODES 1024
#define MARGIN 6e-4f
#define RCAP 48

typedef __attribute__((ext_vector_type(8))) _Float16 half8;
typedef __attribute__((ext_vector_type(4))) float f32x4;

// RNE f32 -> fp16 bits (subnormals handled by HW cvt)
__device__ __forceinline__ unsigned short f2h(float x) {
    __half h = __float2half(x);
    return *reinterpret_cast<unsigned short*>(&h);
}
__device__ __forceinline__ void gload16(const void* g, void* l) {
    __builtin_amdgcn_global_load_lds(
        (const __attribute__((address_space(1))) void*)g,
        (__attribute__((address_space(3))) void*)l, 16, 0, 0);
}

// ---------------------------------------------------------------------------
// k_prep: [0,128) z2 | [128,132) e2 | [132,2180) z fp16 transpose+swz |
//         [2180,2196) e fp16 swz | [2196,2228) rowCnt zero (+lossAcc)
// fp16 layout: zh = u16 [32768][256] row-major, eh = u16 [1024][256], with
// the 16B-slot XOR swizzle baked in (slot s' of each 64-d slab holds orig
// slot s'^(row&7)) so k_score's linear global_load_lds + ds_read_b128 is
// conflict-free (validated rounds 9-11, SQ_LDS_BANK_CONFLICT = 0).
// NUMERICS: z2/e2 ascending chains bit-identical to validated versions.
// ---------------------------------------------------------------------------
__global__ __launch_bounds__(256) void k_prep(const float* __restrict__ z,
                                              const float* __restrict__ e,
                                              float* __restrict__ z2,
                                              float* __restrict__ e2,
                                              unsigned short* __restrict__ zh,
                                              unsigned short* __restrict__ eh,
                                              int* __restrict__ rowCnt,
                                              float* __restrict__ lossAcc) {
    __shared__ float tile[64][65];
    const int bi = blockIdx.x;
    const int t  = threadIdx.x;
    if (bi < 128) {                    // ---- z2 ----
        int n = bi * 256 + t;
        int b = n >> 10, nl = n & 1023;
        const float* p = z + (size_t)b * (D_DIM * 1024) + nl;
        float s = 0.f;
#pragma unroll 8
        for (int d = 0; d < D_DIM; ++d) {
            float v = p[(size_t)d * 1024];
            s = fmaf(v, v, s);
        }
        z2[n] = s;
    } else if (bi < 132) {             // ---- e2 ----
        int k = (bi - 128) * 256 + t;
        const float4* p = (const float4*)(e + (size_t)k * D_DIM);
        float s = 0.f;
#pragma unroll 4
        for (int c = 0; c < D_DIM / 4; ++c) {
            float4 v = p[c];
            s = fmaf(v.x, v.x, s); s = fmaf(v.y, v.y, s);
            s = fmaf(v.z, v.z, s); s = fmaf(v.w, v.w, s);
        }
        e2[k] = s;
    } else if (bi < 2180) {            // ---- z fp16 transpose + swizzle ----
        int bb = bi - 132;
        int n0 = (bb & 511) * 64;
        int d0 = (bb >> 9) * 64;
        int b = n0 >> 10, nl0 = n0 & 1023;
#pragma unroll 4
        for (int i = 0; i < 16; ++i) {
            int flat = i * 256 + t;
            int dd = flat >> 6, j = flat & 63;
            tile[dd][j] = z[(size_t)b * (D_DIM * 1024) +
                            (size_t)(d0 + dd) * 1024 + nl0 + j];
        }
        __syncthreads();
#pragma unroll
        for (int i = 0; i < 4; ++i) {
            int flat = i * 256 + t;
            int row = flat >> 4, ch = flat & 15;
            int s8p = ch >> 1, half = ch & 1;
            int s8  = s8p ^ (row & 7);
            int ddl = s8 * 8 + half * 4;
            unsigned int h[4];
#pragma unroll
            for (int m2 = 0; m2 < 4; ++m2)
                h[m2] = f2h(tile[ddl + m2][row]);
            uint2 ph = { h[0] | (h[1] << 16), h[2] | (h[3] << 16) };
            size_t off = (size_t)(n0 + row) * 256 + d0 + s8p * 8 + half * 4;
            *(uint2*)(zh + off) = ph;
        }
    } else if (bi < 2196) {            // ---- e fp16 swizzle ----
        int k0 = (bi - 2180) * 64;
#pragma unroll 4
        for (int i = 0; i < 16; ++i) {
            int flat = i * 256 + t;
            int row = flat >> 6, ch = flat & 63;
            int slab = ch >> 4, s8p = (ch >> 1) & 7, half = ch & 1;
            int s8 = s8p ^ (row & 7);
            int d  = slab * 64 + s8 * 8 + half * 4;
            float4 v = *(const float4*)(e + (size_t)(k0 + row) * 256 + d);
            uint2 ph = { (unsigned)f2h(v.x) | ((unsigned)f2h(v.y) << 16),
                         (unsigned)f2h(v.z) | ((unsigned)f2h(v.w) << 16) };
            size_t off = (size_t)(k0 + row) * 256 + slab * 64 + s8p * 8 + half * 4;
            *(uint2*)(eh + off) = ph;
        }
    } else {                           // ---- rowCnt zero ----
        int bb = bi - 2196;
        if (bb == 0 && t == 0) lossAcc[0] = 0.f;
#pragma unroll
        for (int i = 0; i < 4; ++i)
            rowCnt[bb * 1024 + i * 256 + t] = 0;
    }
}

// ---------------------------------------------------------------------------
// k_score: fp16 MFMA GEMM, 128 rows x 128 codes x K=256 per block.
// CHANGE from r11 (bf16 3-MFMA split -> fp16 single): e ~ U(+-2^-10) =>
// dot-err eps ~ 4e-5 (rel 2^-12/operand x worst-row sum 0.08 + subnormal
// ~4e-7 + accum ~2e-6) — split precision was overkill. MFMA count /3,
// ds_read /2, LDS 64->32 KB => 4 blocks/CU = 4 waves/SIMD (r11 was
// latency-bound at 2/SIMD: Occ 18.8%, MfmaUtil 16%). MARGIN 6e-4 covers
// 2*eps + 2*ref-rounding with >2x slack (superset + filter proofs intact).
// kc = bid>>8 XCD co-location kept (r11: FETCH 132->65 MB).
// MFMA layouts (f16 family == bf16 family, validated r6-r11): A row=lane&15,
// k=(lane>>4)*8+j; B col=lane&15 same k; C/D col=lane&15, row=(lane>>4)*4+reg.
// ---------------------------------------------------------------------------
__global__ __launch_bounds__(256) void k_score(
        const unsigned short* __restrict__ zh,
        const unsigned short* __restrict__ eh,
        const float* __restrict__ e2,
        int* __restrict__ rowCnt, uint2* __restrict__ rowCand) {
    __shared__ unsigned short Ah[8192], Bh[8192];   // 32 KB

    const int t    = threadIdx.x;
    const int lane = t & 63;
    const int w    = t >> 6;
    const int wrow = w >> 1, wcol = w & 1;
    const int kc   = blockIdx.x >> 8;      // XCD co-location decode
    const int rb   = blockIdx.x & 255;
    const int n0   = rb * 128, k0 = kc * 128;
    const int c    = lane & 15, kq = lane >> 4;

    f32x4 acc[4][4];
#pragma unroll
    for (int rf = 0; rf < 4; ++rf)
#pragma unroll
        for (int cf = 0; cf < 4; ++cf)
            acc[rf][cf] = (f32x4){0.f, 0.f, 0.f, 0.f};

    for (int sl = 0; sl < 4; ++sl) {
        // stage A,B fp16 tiles (16 KB each): slot = i*256+t, row=slot>>3
#pragma unroll
        for (int i = 0; i < 4; ++i) {
            int slot = i * 256 + t;
            int row = slot >> 3, s16 = slot & 7;
            size_t aoff = (size_t)(n0 + row) * 256 + sl * 64 + s16 * 8;
            size_t boff = (size_t)(k0 + row) * 256 + sl * 64 + s16 * 8;
            int dbase = (i * 256 + w * 64) * 8;
            gload16(zh + aoff, &Ah[dbase]);
            gload16(eh + boff, &Bh[dbase]);
        }
        __syncthreads();
#pragma unroll
        for (int ks = 0; ks < 2; ++ks) {
            half8 ah[4], bh[4];
#pragma unroll
            for (int rf = 0; rf < 4; ++rf) {
                int rl = wrow * 64 + rf * 16 + c;
                int sp = (ks * 4 + kq) ^ (rl & 7);
                ah[rf] = *(const half8*)&Ah[rl * 64 + sp * 8];
            }
#pragma unroll
            for (int cf = 0; cf < 4; ++cf) {
                int cl = wcol * 64 + cf * 16 + c;
                int sp = (ks * 4 + kq) ^ (cl & 7);
                bh[cf] = *(const half8*)&Bh[cl * 64 + sp * 8];
            }
#pragma unroll
            for (int rf = 0; rf < 4; ++rf)
#pragma unroll
                for (int cf = 0; cf < 4; ++cf)
                    acc[rf][cf] = __builtin_amdgcn_mfma_f32_16x16x32_f16(
                        ah[rf], bh[cf], acc[rf][cf], 0, 0, 0);
        }
        __syncthreads();
    }

    // ---- epilogue: s = e2[k] - 2*ze; capture s <= wave-row-min + MARGIN ----
    float e2r[4];
#pragma unroll
    for (int cf = 0; cf < 4; ++cf) e2r[cf] = e2[k0 + wcol * 64 + cf * 16 + c];

    float rmin[4][4];
#pragma unroll
    for (int rf = 0; rf < 4; ++rf)
#pragma unroll
        for (int reg = 0; reg < 4; ++reg) {
            float mm = 3.4e38f;
#pragma unroll
            for (int cf = 0; cf < 4; ++cf)
                mm = fminf(mm, fmaf(-2.f, acc[rf][cf][reg], e2r[cf]));
            rmin[rf][reg] = mm;
        }
#pragma unroll
    for (int m = 1; m < 16; m <<= 1)
#pragma unroll
        for (int rf = 0; rf < 4; ++rf)
#pragma unroll
            for (int reg = 0; reg < 4; ++reg)
                rmin[rf][reg] = fminf(rmin[rf][reg],
                                      __shfl_xor(rmin[rf][reg], m, 64));

#pragma unroll
    for (int rf = 0; rf < 4; ++rf)
#pragma unroll
        for (int cf = 0; cf < 4; ++cf)
#pragma unroll
            for (int reg = 0; reg < 4; ++reg) {
                float s = fmaf(-2.f, acc[rf][cf][reg], e2r[cf]);
                if (s <= rmin[rf][reg] + MARGIN) {
                    int n = n0 + wrow * 64 + rf * 16 + kq * 4 + reg;
                    int k = k0 + wcol * 64 + cf * 16 + c;
                    int pos = atomicAdd(&rowCnt[n], 1);
                    if (pos < RCAP) {
                        uint2 cd; cd.x = (unsigned)k; cd.y = __float_as_uint(s);
                        rowCand[n * RCAP + pos] = cd;
                    }
                }
            }
}

// ---------------------------------------------------------------------------
// k_select: global-min filter + exact rescore of survivors (validated r10/11).
// Non-survivor k: s_a(k) > gmin+M => d_ref(k) > d_ref(best survivor) +
// (M - 2*eps - 2*delta) > 0 with M=6e-4, eps~1e-4, delta~6e-5 => cannot win
// or tie. Sole survivor == ref argmin. Exact path: validated ascending-d
// fp32 chain, dist = fmaf(-2, ze, fl(z2+e2)); packed (distbits<<32|k) min ==
// np first-index tie-break. cnt > RCAP => deterministic full 1024-code scan.
// ---------------------------------------------------------------------------
__global__ __launch_bounds__(256) void k_select(
        const float* __restrict__ z, const float* __restrict__ e,
        const float* __restrict__ z2a, const float* __restrict__ e2,
        const int* __restrict__ rowCnt, const uint2* __restrict__ rowCand,
        float* __restrict__ outIdx, int* __restrict__ wsIdx) {
    const int t = threadIdx.x, lane = t & 63, w = t >> 6;
    const int wid = blockIdx.x * 4 + w;       // 0..4095
    for (int rr = 0; rr < 8; ++rr) {
        const int n = wid * 8 + rr;
        const int cnt = rowCnt[n];
        const float* zrow = z + (size_t)(n >> 10) * (D_DIM * 1024) + (n & 1023);
        unsigned long long key = 0xFFFFFFFFFFFFFFFFULL;
        if (cnt <= RCAP) {
            float s = 3.4e38f;
            int   k = 0;
            if (lane < cnt) {
                uint2 cd = rowCand[n * RCAP + lane];
                k = (int)cd.x;
                s = __uint_as_float(cd.y);
            }
            float gmin = s;
#pragma unroll
            for (int m = 1; m < 64; m <<= 1)
                gmin = fminf(gmin, __shfl_xor(gmin, m, 64));
            bool surv = (lane < cnt) && (s <= gmin + MARGIN);
            unsigned long long bal = __ballot(surv);
            if (__popcll(bal) == 1) {            // sole survivor == argmin
                if (surv) { outIdx[n] = (float)k; wsIdx[n] = k; }
                continue;                         // bal wave-uniform
            }
            if (surv) {
                const float* er = e + (size_t)k * D_DIM;
                float ze = 0.f;
#pragma unroll 8
                for (int d = 0; d < D_DIM; ++d)
                    ze = fmaf(zrow[(size_t)d * 1024], er[d], ze);
                float t1 = z2a[n] + e2[k];
                float dist = fmaf(-2.f, ze, t1);
                key = ((unsigned long long)__float_as_uint(dist) << 32) |
                      (unsigned int)k;
            }
        } else {                      // deterministic fallback: full scan
            const float z2r = z2a[n];
            for (int j = 0; j < 16; ++j) {
                int k = lane * 16 + j;
                const float* er = e + (size_t)k * D_DIM;
                float ze = 0.f;
#pragma unroll 8
                for (int d = 0; d < D_DIM; ++d)
                    ze = fmaf(zrow[(size_t)d * 1024], er[d], ze);
                float t1 = z2r + e2[k];
                float dist = fmaf(-2.f, ze, t1);
                unsigned long long kk =
                    ((unsigned long long)__float_as_uint(dist) << 32) |
                    (unsigned int)k;
                if (kk < key) key = kk;
            }
        }
#pragma unroll
        for (int m = 1; m < 64; m <<= 1) {
            unsigned long long o = __shfl_xor(key, m, 64);
            if (o < key) key = o;
        }
        if (lane == 0) {
            int k = (int)(unsigned int)(key & 0xFFFFFFFFULL);
            outIdx[n] = (float)k;
            wsIdx[n]  = k;
        }
    }
}

// ---------------------------------------------------------------------------
// Epilogue: 32 rows x 256 d per block, grid 1024, 4 blocks/CU (r11 version).
// ---------------------------------------------------------------------------
__global__ __launch_bounds__(256) void k_epilogue(const float* __restrict__ z,
                                                  const float* __restrict__ e,
                                                  const int* __restrict__ wsIdx,
                                                  float* __restrict__ outZ,
                                                  float* __restrict__ lossAcc) {
    __shared__ float4 zq4[32][64];
    __shared__ int idxs[32];
    const int t = threadIdx.x;
    const int n0 = blockIdx.x * 32;
    const int b = n0 >> 10, nl0 = n0 & 1023;

    if (t < 32) idxs[t] = wsIdx[n0 + t];
    __syncthreads();

#pragma unroll
    for (int j = 0; j < 8; ++j) {
        int flat = j * 256 + t;
        int i  = flat >> 6;
        int c4 = flat & 63;
        float4 v = *(const float4*)(e + (size_t)idxs[i] * D_DIM + c4 * 4);
        zq4[i][c4 ^ (i & 7)] = v;
    }
    __syncthreads();

    const int i  = t & 31;
    const int dg = t >> 5;
    const float* zp = z    + (size_t)b * (D_DIM * 1024) + nl0 + i;
    float*       op = outZ + (size_t)b * (D_DIM * 1024) + nl0 + i;
    float s = 0.f;
#pragma unroll 4
    for (int c = 0; c < 8; ++c) {
        int c4 = dg * 8 + c;
        float4 qv = zq4[i][c4 ^ (i & 7)];
        int d = c4 * 4;
        float zv, df;
        zv = zp[(size_t)(d + 0) * 1024]; df = qv.x - zv; s = fmaf(df, df, s); op[(size_t)(d + 0) * 1024] = zv + df;
        zv = zp[(size_t)(d + 1) * 1024]; df = qv.y - zv; s = fmaf(df, df, s); op[(size_t)(d + 1) * 1024] = zv + df;
        zv = zp[(size_t)(d + 2) * 1024]; df = qv.z - zv; s = fmaf(df, df, s); op[(size_t)(d + 2) * 1024] = zv + df;
        zv = zp[(size_t)(d + 3) * 1024]; df = qv.w - zv; s = fmaf(df, df, s); op[(size_t)(d + 3) * 1024] = zv + df;
    }
#pragma unroll
    for (int off = 32; off > 0; off >>= 1) s += __shfl_down(s, off, 64);
    if ((t & 63) == 0) atomicAdd(lossAcc, s);
}

__global__ void k_final(const float* __restrict__ lossAcc,
                        float* __restrict__ outLoss) {
    float m = lossAcc[0] * (1.0f / 8388608.0f);
    outLoss[0] = m + 0.25f * m;
}

// ---------------------------------------------------------------------------
extern "C" void kernel_launch(void* const* d_in, const int* in_sizes, int n_in,
                              void* d_out, int out_size, void* d_ws, size_t ws_size,
                              hipStream_t stream) {
    const float* z = (const float*)d_in[0];   // (32,256,32,32)
    const float* e = (const float*)d_in[1];   // (1024,256)
    float* out     = (float*)d_out;
    float* outIdx  = out + 8388608;
    float* outLoss = out + 8421376;

    float* z2      = (float*)d_ws;                        // 32768 f
    float* e2      = z2 + 32768;                          // 1024 f
    float* lossAcc = e2 + 1024;                           // 1 f
    int*   rowCnt  = (int*)(lossAcc + 1);                 // 32768 i
    uintptr_t p = (uintptr_t)(rowCnt + 32768);
    p = (p + 255) & ~(uintptr_t)255;
    uint2* rowCand = (uint2*)p;                           // 32768*48 uint2 = 12 MB
    unsigned short* zh = (unsigned short*)(rowCand + 32768 * RCAP); // 16 MB
    unsigned short* eh = zh + 8388608;                    // 512 KB
    int*   wsIdx   = (int*)(eh + 262144);                 // 32768 i

    k_prep<<<2228, 256, 0, stream>>>(z, e, z2, e2, zh, eh, rowCnt, lossAcc);
    k_score<<<2048, 256, 0, stream>>>(zh, eh, e2, rowCnt, rowCand);
    k_select<<<1024, 256, 0, stream>>>(z, e, z2, e2, rowCnt, rowCand,
                                       outIdx, wsIdx);
    k_epilogue<<<1024, 256, 0, stream>>>(z, e, wsIdx, out, lossAcc);
    k_final<<<1, 1, 0, stream>>>(lossAcc, outLoss);
}

// Round 13
// 188.206 us; speedup vs baseline: 1.3845x; 1.2894x over previous
//
#include <hip/hip_runtime.h>
#include <hip/hip_fp16.h>

#define D_DIM 256
#define K_CODES 1024
#define MARGIN 6e-4f
#define RCAP 48

typedef __attribute__((ext_vector_type(8))) _Float16 half8;
typedef __attribute__((ext_vector_type(4))) float f32x4;

// RNE f32 -> fp16 bits (validated r12)
__device__ __forceinline__ unsigned short f2h(float x) {
    __half h = __float2half(x);
    return *reinterpret_cast<unsigned short*>(&h);
}
__device__ __forceinline__ void gload16(const void* g, void* l) {
    __builtin_amdgcn_global_load_lds(
        (const __attribute__((address_space(1))) void*)g,
        (__attribute__((address_space(3))) void*)l, 16, 0, 0);
}

// ---------------------------------------------------------------------------
// k_prep: [0,128) z2 | [128,132) e2 | [132,2180) z fp16 transpose+swz |
//         [2180,2196) e fp16 swz | [2196,2228) rowCnt zero (+lossAcc)
// (unchanged from validated round 12)
// ---------------------------------------------------------------------------
__global__ __launch_bounds__(256) void k_prep(const float* __restrict__ z,
                                              const float* __restrict__ e,
                                              float* __restrict__ z2,
                                              float* __restrict__ e2,
                                              unsigned short* __restrict__ zh,
                                              unsigned short* __restrict__ eh,
                                              int* __restrict__ rowCnt,
                                              float* __restrict__ lossAcc) {
    __shared__ float tile[64][65];
    const int bi = blockIdx.x;
    const int t  = threadIdx.x;
    if (bi < 128) {                    // ---- z2 ----
        int n = bi * 256 + t;
        int b = n >> 10, nl = n & 1023;
        const float* p = z + (size_t)b * (D_DIM * 1024) + nl;
        float s = 0.f;
#pragma unroll 8
        for (int d = 0; d < D_DIM; ++d) {
            float v = p[(size_t)d * 1024];
            s = fmaf(v, v, s);
        }
        z2[n] = s;
    } else if (bi < 132) {             // ---- e2 ----
        int k = (bi - 128) * 256 + t;
        const float4* p = (const float4*)(e + (size_t)k * D_DIM);
        float s = 0.f;
#pragma unroll 4
        for (int c = 0; c < D_DIM / 4; ++c) {
            float4 v = p[c];
            s = fmaf(v.x, v.x, s); s = fmaf(v.y, v.y, s);
            s = fmaf(v.z, v.z, s); s = fmaf(v.w, v.w, s);
        }
        e2[k] = s;
    } else if (bi < 2180) {            // ---- z fp16 transpose + swizzle ----
        int bb = bi - 132;
        int n0 = (bb & 511) * 64;
        int d0 = (bb >> 9) * 64;
        int b = n0 >> 10, nl0 = n0 & 1023;
#pragma unroll 4
        for (int i = 0; i < 16; ++i) {
            int flat = i * 256 + t;
            int dd = flat >> 6, j = flat & 63;
            tile[dd][j] = z[(size_t)b * (D_DIM * 1024) +
                            (size_t)(d0 + dd) * 1024 + nl0 + j];
        }
        __syncthreads();
#pragma unroll
        for (int i = 0; i < 4; ++i) {
            int flat = i * 256 + t;
            int row = flat >> 4, ch = flat & 15;
            int s8p = ch >> 1, half = ch & 1;
            int s8  = s8p ^ (row & 7);
            int ddl = s8 * 8 + half * 4;
            unsigned int h[4];
#pragma unroll
            for (int m2 = 0; m2 < 4; ++m2)
                h[m2] = f2h(tile[ddl + m2][row]);
            uint2 ph = { h[0] | (h[1] << 16), h[2] | (h[3] << 16) };
            size_t off = (size_t)(n0 + row) * 256 + d0 + s8p * 8 + half * 4;
            *(uint2*)(zh + off) = ph;
        }
    } else if (bi < 2196) {            // ---- e fp16 swizzle ----
        int k0 = (bi - 2180) * 64;
#pragma unroll 4
        for (int i = 0; i < 16; ++i) {
            int flat = i * 256 + t;
            int row = flat >> 6, ch = flat & 63;
            int slab = ch >> 4, s8p = (ch >> 1) & 7, half = ch & 1;
            int s8 = s8p ^ (row & 7);
            int d  = slab * 64 + s8 * 8 + half * 4;
            float4 v = *(const float4*)(e + (size_t)(k0 + row) * 256 + d);
            uint2 ph = { (unsigned)f2h(v.x) | ((unsigned)f2h(v.y) << 16),
                         (unsigned)f2h(v.z) | ((unsigned)f2h(v.w) << 16) };
            size_t off = (size_t)(k0 + row) * 256 + slab * 64 + s8p * 8 + half * 4;
            *(uint2*)(eh + off) = ph;
        }
    } else {                           // ---- rowCnt zero ----
        int bb = bi - 2196;
        if (bb == 0 && t == 0) lossAcc[0] = 0.f;
#pragma unroll
        for (int i = 0; i < 4; ++i)
            rowCnt[bb * 1024 + i * 256 + t] = 0;
    }
}

// ---------------------------------------------------------------------------
// k_score v3: persistent-style blocks. Grid 512 x 512 thr (8 waves) = exactly
// 2 blocks/CU, ONE dispatch generation (r10-12 ran 1.4 blocks/CU avg across
// 8 launch generations of 4-stage pipelines — all fill/drain). Block = 64
// rows x ALL 1024 codes: A panel (64x256 fp16, 32 KB) resident, staged once;
// B streamed in 32 dbuf slabs (128 codes x 64 d, 16 KB) -> 32-stage pipeline,
// stage s+1 issued before computing s, one barrier/stage (r4-validated).
// LDS 64 KB static. Wave (wr=w>>1, wc=w&1) = 16 rows x 64 codes; per stage
// 2 ks x (1 A + 4 B ds_b128 -> 4 MFMA). 64-d slab granularity keeps the
// baked XOR swizzle self-contained (reads 2-way = free, validated r9-12).
// Capture after each kc (8x) vs per-wave running min m_run (>= gmin => 
// captured set superset of {s <= gmin + MARGIN}; k_select's filter + exact
// rescore unchanged; overflow fallback unchanged). Scores bitwise same form
// as r12: s = fmaf(-2, acc, e2[k]).
// ---------------------------------------------------------------------------
__global__ __launch_bounds__(512) void k_score(
        const unsigned short* __restrict__ zh,
        const unsigned short* __restrict__ eh,
        const float* __restrict__ e2,
        int* __restrict__ rowCnt, uint2* __restrict__ rowCand) {
    __shared__ unsigned short lds[32768];  // A[0,16384) | B0[16384,24576) | B1[24576,32768)

    const int t    = threadIdx.x;          // 0..511
    const int lane = t & 63;
    const int w    = t >> 6;               // 0..7
    const int wr   = w >> 1;               // row-group 0..3
    const int wc   = w & 1;                // code-half 0..1
    const int c    = lane & 15;
    const int kq   = lane >> 4;            // 0..3
    const int n0   = blockIdx.x * 64;

    // ---- stage A panel (64 rows x 256 d = 32 KB), linear DMA, swz baked ----
#pragma unroll
    for (int p = 0; p < 4; ++p) {
        int slot = p * 512 + t;            // 2048 slots of 16B
        int row  = slot >> 5, sg = slot & 31;
        gload16(zh + (size_t)(n0 + row) * 256 + sg * 8,
                &lds[(p * 512 + w * 64) * 8]);
    }

#define STAGE_B(S, BUF)                                                      \
    do {                                                                     \
        int kc_ = (S) >> 2, dg_ = (S) & 3;                                   \
        _Pragma("unroll")                                                    \
        for (int p = 0; p < 2; ++p) {                                        \
            int slot = p * 512 + t;         /* 1024 slots of 16B */          \
            int code = slot >> 3, sg = slot & 7;                             \
            gload16(eh + (size_t)(kc_ * 128 + code) * 256 + dg_ * 64 + sg * 8, \
                    &lds[16384 + (BUF) * 8192 + (p * 512 + w * 64) * 8]);    \
        }                                                                    \
    } while (0)

    f32x4 acc[4];
#pragma unroll
    for (int cf = 0; cf < 4; ++cf) acc[cf] = (f32x4){0.f, 0.f, 0.f, 0.f};
    float m_run[4] = { 3.4e38f, 3.4e38f, 3.4e38f, 3.4e38f };

    const int rl = wr * 16 + c;            // this lane's A row
    STAGE_B(0, 0);
    __syncthreads();

    for (int s = 0; s < 32; ++s) {
        if (s < 31) STAGE_B(s + 1, (s + 1) & 1);
        // ---- compute slab s: d-group dg, buffer s&1 ----
        {
            const int dg = s & 3;
            const unsigned short* Bb = &lds[16384 + (s & 1) * 8192];
#pragma unroll
            for (int ks = 0; ks < 2; ++ks) {
                int wo = ks * 4 + kq;
                half8 a = *(const half8*)&lds[rl * 256 + dg * 64 +
                                              (wo ^ (rl & 7)) * 8];
                half8 b[4];
#pragma unroll
                for (int cf = 0; cf < 4; ++cf) {
                    int cl = wc * 64 + cf * 16 + c;
                    b[cf] = *(const half8*)&Bb[cl * 64 + (wo ^ (cl & 7)) * 8];
                }
#pragma unroll
                for (int cf = 0; cf < 4; ++cf)
                    acc[cf] = __builtin_amdgcn_mfma_f32_16x16x32_f16(
                        a, b[cf], acc[cf], 0, 0, 0);
            }
        }
        if ((s & 3) == 3) {
            // ---- capture for kc = s>>2 ----
            const int kc = s >> 2;
            float e2r[4];
#pragma unroll
            for (int cf = 0; cf < 4; ++cf)
                e2r[cf] = e2[kc * 128 + wc * 64 + cf * 16 + c];
            float mnew[4];
#pragma unroll
            for (int reg = 0; reg < 4; ++reg) {
                float mm = 3.4e38f;
#pragma unroll
                for (int cf = 0; cf < 4; ++cf)
                    mm = fminf(mm, fmaf(-2.f, acc[cf][reg], e2r[cf]));
                mnew[reg] = mm;
            }
#pragma unroll
            for (int m = 1; m < 16; m <<= 1)
#pragma unroll
                for (int reg = 0; reg < 4; ++reg)
                    mnew[reg] = fminf(mnew[reg], __shfl_xor(mnew[reg], m, 64));
#pragma unroll
            for (int reg = 0; reg < 4; ++reg)
                mnew[reg] = fminf(mnew[reg], m_run[reg]);
#pragma unroll
            for (int cf = 0; cf < 4; ++cf)
#pragma unroll
                for (int reg = 0; reg < 4; ++reg) {
                    float sv = fmaf(-2.f, acc[cf][reg], e2r[cf]);
                    if (sv <= mnew[reg] + MARGIN) {
                        int n = n0 + wr * 16 + kq * 4 + reg;
                        int k = kc * 128 + wc * 64 + cf * 16 + c;
                        int pos = atomicAdd(&rowCnt[n], 1);
                        if (pos < RCAP) {
                            uint2 cd; cd.x = (unsigned)k;
                            cd.y = __float_as_uint(sv);
                            rowCand[n * RCAP + pos] = cd;
                        }
                    }
                }
#pragma unroll
            for (int reg = 0; reg < 4; ++reg) m_run[reg] = mnew[reg];
#pragma unroll
            for (int cf = 0; cf < 4; ++cf) acc[cf] = (f32x4){0.f, 0.f, 0.f, 0.f};
        }
        __syncthreads();
    }
#undef STAGE_B
}

// ---------------------------------------------------------------------------
// k_select: global-min filter + exact rescore of survivors (validated r10-12).
// ---------------------------------------------------------------------------
__global__ __launch_bounds__(256) void k_select(
        const float* __restrict__ z, const float* __restrict__ e,
        const float* __restrict__ z2a, const float* __restrict__ e2,
        const int* __restrict__ rowCnt, const uint2* __restrict__ rowCand,
        float* __restrict__ outIdx, int* __restrict__ wsIdx) {
    const int t = threadIdx.x, lane = t & 63, w = t >> 6;
    const int wid = blockIdx.x * 4 + w;       // 0..4095
    for (int rr = 0; rr < 8; ++rr) {
        const int n = wid * 8 + rr;
        const int cnt = rowCnt[n];
        const float* zrow = z + (size_t)(n >> 10) * (D_DIM * 1024) + (n & 1023);
        unsigned long long key = 0xFFFFFFFFFFFFFFFFULL;
        if (cnt <= RCAP) {
            float s = 3.4e38f;
            int   k = 0;
            if (lane < cnt) {
                uint2 cd = rowCand[n * RCAP + lane];
                k = (int)cd.x;
                s = __uint_as_float(cd.y);
            }
            float gmin = s;
#pragma unroll
            for (int m = 1; m < 64; m <<= 1)
                gmin = fminf(gmin, __shfl_xor(gmin, m, 64));
            bool surv = (lane < cnt) && (s <= gmin + MARGIN);
            unsigned long long bal = __ballot(surv);
            if (__popcll(bal) == 1) {            // sole survivor == argmin
                if (surv) { outIdx[n] = (float)k; wsIdx[n] = k; }
                continue;                         // bal wave-uniform
            }
            if (surv) {
                const float* er = e + (size_t)k * D_DIM;
                float ze = 0.f;
#pragma unroll 8
                for (int d = 0; d < D_DIM; ++d)
                    ze = fmaf(zrow[(size_t)d * 1024], er[d], ze);
                float t1 = z2a[n] + e2[k];
                float dist = fmaf(-2.f, ze, t1);
                key = ((unsigned long long)__float_as_uint(dist) << 32) |
                      (unsigned int)k;
            }
        } else {                      // deterministic fallback: full scan
            const float z2r = z2a[n];
            for (int j = 0; j < 16; ++j) {
                int k = lane * 16 + j;
                const float* er = e + (size_t)k * D_DIM;
                float ze = 0.f;
#pragma unroll 8
                for (int d = 0; d < D_DIM; ++d)
                    ze = fmaf(zrow[(size_t)d * 1024], er[d], ze);
                float t1 = z2r + e2[k];
                float dist = fmaf(-2.f, ze, t1);
                unsigned long long kk =
                    ((unsigned long long)__float_as_uint(dist) << 32) |
                    (unsigned int)k;
                if (kk < key) key = kk;
            }
        }
#pragma unroll
        for (int m = 1; m < 64; m <<= 1) {
            unsigned long long o = __shfl_xor(key, m, 64);
            if (o < key) key = o;
        }
        if (lane == 0) {
            int k = (int)(unsigned int)(key & 0xFFFFFFFFULL);
            outIdx[n] = (float)k;
            wsIdx[n]  = k;
        }
    }
}

// ---------------------------------------------------------------------------
// Epilogue: 32 rows x 256 d per block, grid 1024 (validated r11/r12).
// ---------------------------------------------------------------------------
__global__ __launch_bounds__(256) void k_epilogue(const float* __restrict__ z,
                                                  const float* __restrict__ e,
                                                  const int* __restrict__ wsIdx,
                                                  float* __restrict__ outZ,
                                                  float* __restrict__ lossAcc) {
    __shared__ float4 zq4[32][64];
    __shared__ int idxs[32];
    const int t = threadIdx.x;
    const int n0 = blockIdx.x * 32;
    const int b = n0 >> 10, nl0 = n0 & 1023;

    if (t < 32) idxs[t] = wsIdx[n0 + t];
    __syncthreads();

#pragma unroll
    for (int j = 0; j < 8; ++j) {
        int flat = j * 256 + t;
        int i  = flat >> 6;
        int c4 = flat & 63;
        float4 v = *(const float4*)(e + (size_t)idxs[i] * D_DIM + c4 * 4);
        zq4[i][c4 ^ (i & 7)] = v;
    }
    __syncthreads();

    const int i  = t & 31;
    const int dg = t >> 5;
    const float* zp = z    + (size_t)b * (D_DIM * 1024) + nl0 + i;
    float*       op = outZ + (size_t)b * (D_DIM * 1024) + nl0 + i;
    float s = 0.f;
#pragma unroll 4
    for (int c = 0; c < 8; ++c) {
        int c4 = dg * 8 + c;
        float4 qv = zq4[i][c4 ^ (i & 7)];
        int d = c4 * 4;
        float zv, df;
        zv = zp[(size_t)(d + 0) * 1024]; df = qv.x - zv; s = fmaf(df, df, s); op[(size_t)(d + 0) * 1024] = zv + df;
        zv = zp[(size_t)(d + 1) * 1024]; df = qv.y - zv; s = fmaf(df, df, s); op[(size_t)(d + 1) * 1024] = zv + df;
        zv = zp[(size_t)(d + 2) * 1024]; df = qv.z - zv; s = fmaf(df, df, s); op[(size_t)(d + 2) * 1024] = zv + df;
        zv = zp[(size_t)(d + 3) * 1024]; df = qv.w - zv; s = fmaf(df, df, s); op[(size_t)(d + 3) * 1024] = zv + df;
    }
#pragma unroll
    for (int off = 32; off > 0; off >>= 1) s += __shfl_down(s, off, 64);
    if ((t & 63) == 0) atomicAdd(lossAcc, s);
}

__global__ void k_final(const float* __restrict__ lossAcc,
                        float* __restrict__ outLoss) {
    float m = lossAcc[0] * (1.0f / 8388608.0f);
    outLoss[0] = m + 0.25f * m;
}

// ---------------------------------------------------------------------------
extern "C" void kernel_launch(void* const* d_in, const int* in_sizes, int n_in,
                              void* d_out, int out_size, void* d_ws, size_t ws_size,
                              hipStream_t stream) {
    const float* z = (const float*)d_in[0];   // (32,256,32,32)
    const float* e = (const float*)d_in[1];   // (1024,256)
    float* out     = (float*)d_out;
    float* outIdx  = out + 8388608;
    float* outLoss = out + 8421376;

    float* z2      = (float*)d_ws;                        // 32768 f
    float* e2      = z2 + 32768;                          // 1024 f
    float* lossAcc = e2 + 1024;                           // 1 f
    int*   rowCnt  = (int*)(lossAcc + 1);                 // 32768 i
    uintptr_t p = (uintptr_t)(rowCnt + 32768);
    p = (p + 255) & ~(uintptr_t)255;
    uint2* rowCand = (uint2*)p;                           // 32768*48 uint2 = 12 MB
    unsigned short* zh = (unsigned short*)(rowCand + 32768 * RCAP); // 16 MB
    unsigned short* eh = zh + 8388608;                    // 512 KB
    int*   wsIdx   = (int*)(eh + 262144);                 // 32768 i

    k_prep<<<2228, 256, 0, stream>>>(z, e, z2, e2, zh, eh, rowCnt, lossAcc);
    k_score<<<512, 512, 0, stream>>>(zh, eh, e2, rowCnt, rowCand);
    k_select<<<1024, 256, 0, stream>>>(z, e, z2, e2, rowCnt, rowCand,
                                       outIdx, wsIdx);
    k_epilogue<<<1024, 256, 0, stream>>>(z, e, wsIdx, out, lossAcc);
    k_final<<<1, 1, 0, stream>>>(lossAcc, outLoss);
}